// Round 4
// baseline (278.663 us; speedup 1.0000x reference)
//
#include <hip/hip_runtime.h>
#include <hip/hip_bf16.h>

#define Nn 50000
#define DEG 16
#define IN_F 512
#define HID 128
#define OUT_F 64
#define SLOPE 0.2f

typedef __attribute__((ext_vector_type(8))) short bf16x8;
typedef __attribute__((ext_vector_type(4))) float f32x4;

__device__ __forceinline__ unsigned short f2bf(float f) {
    return __builtin_bit_cast(unsigned short, __float2bfloat16(f));
}
__device__ __forceinline__ float bf2f(unsigned short u) {
    return __bfloat162float(__builtin_bit_cast(__hip_bfloat16, u));
}

// ---------- prep: W1/W2 -> [F][K] bf16. Coalesced READS, scattered writes ----------
__global__ void __launch_bounds__(256) prep_kernel(
        const float* __restrict__ W1, const float* __restrict__ W2,
        const int* __restrict__ row_ptr,
        unsigned short* __restrict__ w1t, unsigned short* __restrict__ w2t,
        int* __restrict__ flag64) {
    int g = blockIdx.x * 256 + threadIdx.x;
    if (g == 0) {
        // int32 layout: row_ptr words = [0,16,32,...]; int64: [0,0,16,0,...]
        *flag64 = (row_ptr[1] == DEG) ? 0 : 1;
    }
    if (g < IN_F * HID) {                     // read W1 linearly: k = g>>7, c = g&127
        int k = g >> 7, c = g & 127;
        w1t[c * IN_F + k] = f2bf(W1[g]);      // scattered 2B write (fire-and-forget)
    } else {
        int g2 = g - IN_F * HID;
        if (g2 < HID * OUT_F) {               // k = g2>>6, c = g2&63
            int k = g2 >> 6, c = g2 & 63;
            w2t[c * HID + k] = f2bf(W2[g2]);
        }
    }
}

// ---------- layer-1 GEMM: barrier-free, 16 rows x 128 cols per wave ----------
// grid = ceil(N/64) = 782 blocks -> ~3 waves/SIMD (vs 1.5 in round 3).
// Each wave: 1 A-frag (16 rows, fp32->bf16 in-register) x NT=8 B-frags
// (WT [F][K] bf16, L2-resident) per ks; fused el/er epilogue (full-F in-wave).
template<int K, int F>
__global__ void __launch_bounds__(256) gemm1_reg(
        const float* __restrict__ Af, const unsigned short* __restrict__ WT,
        const float* __restrict__ alv, const float* __restrict__ arv,
        unsigned short* __restrict__ Hb, float* __restrict__ el,
        float* __restrict__ er, int M) {
    constexpr int NT = F / 16;
    const int tid  = threadIdx.x;
    const int lane = tid & 63;
    const int w    = tid >> 6;
    const int ln   = lane & 15, q = lane >> 4;
    const int mb   = blockIdx.x * 64 + w * 16;

    int m0 = mb + ln; if (m0 > M - 1) m0 = M - 1;
    const float* a0p = Af + (size_t)m0 * K;

    f32x4 acc[NT] = {};

    #pragma unroll
    for (int ks = 0; ks < K / 32; ++ks) {
        const int kk = ks * 32 + q * 8;       // A[m][k]: m=lane&15, k=q*8+j
        f32x4 va0 = *(const f32x4*)(a0p + kk);
        f32x4 va1 = *(const f32x4*)(a0p + kk + 4);
        bf16x8 af;
        #pragma unroll
        for (int jj = 0; jj < 4; ++jj) {
            af[jj]     = (short)f2bf(va0[jj]);
            af[jj + 4] = (short)f2bf(va1[jj]);
        }
        #pragma unroll
        for (int nt = 0; nt < NT; ++nt) {
            bf16x8 bfr = *(const bf16x8*)&WT[(size_t)(nt * 16 + ln) * K + kk];
            acc[nt] = __builtin_amdgcn_mfma_f32_16x16x32_bf16(af, bfr, acc[nt], 0, 0, 0);
        }
    }

    // ---- fused epilogue: bf16 H store + el/er row dots (pure in-wave) ----
    // D layout: col = ln, row = q*4 + reg  [measured m89/m91]
    float av[NT], bv[NT];
    #pragma unroll
    for (int nt = 0; nt < NT; ++nt) {
        av[nt] = alv[nt * 16 + ln];
        bv[nt] = arv[nt * 16 + ln];
    }
    #pragma unroll
    for (int r = 0; r < 4; ++r) {
        float sl = 0.f, sr = 0.f;
        #pragma unroll
        for (int nt = 0; nt < NT; ++nt) {
            float v = acc[nt][r];
            sl += v * av[nt];
            sr += v * bv[nt];
        }
        #pragma unroll
        for (int m = 1; m < 16; m <<= 1) {    // reduce across 16-lane col group
            sl += __shfl_xor(sl, m);
            sr += __shfl_xor(sr, m);
        }
        int grow = mb + q * 4 + r;
        if (grow < M) {
            #pragma unroll
            for (int nt = 0; nt < NT; ++nt)
                Hb[(size_t)grow * F + nt * 16 + ln] = f2bf(acc[nt][r]);
            if (ln == 0) { el[grow] = sl; er[grow] = sr; }
        }
    }
}

// ---------- fused layer-1 aggregation + layer-2 GEMM + el2/er2 ----------
// Block = 16 nodes. Phase A: 4 waves x 4 nodes: softmax over 16 edges +
// gather of h1 rows (coalesced 256B reads), out1 tile -> LDS bf16 (never
// touches HBM). Phase B: 16x64 MFMA tile, K=128 from LDS (stride 136:
// conflict-free b128 reads), W2T frags from L2; fused el2/er2 epilogue.
__global__ void __launch_bounds__(256) fused_agg_gemm2(
        const int* __restrict__ col, const int* __restrict__ flag64,
        const float* __restrict__ el1, const float* __restrict__ er1,
        const unsigned short* __restrict__ Hb, const float* __restrict__ b1,
        const unsigned short* __restrict__ w2t,
        const float* __restrict__ al2, const float* __restrict__ ar2,
        unsigned short* __restrict__ H2, float* __restrict__ el2,
        float* __restrict__ er2) {
    constexpr int STR = 136;                  // 128 + 8 bf16 pad
    __shared__ unsigned short at[16 * STR];
    __shared__ float redl[16][4];
    __shared__ float redr[16][4];

    const int tid  = threadIdx.x;
    const int lane = tid & 63;
    const int w    = tid >> 6;
    const int ln   = lane & 15, q = lane >> 4;
    const int nb   = blockIdx.x * 16;
    const int use64 = *flag64;

    // ---- phase A: aggregate 4 nodes per wave ----
    #pragma unroll
    for (int n = 0; n < 4; ++n) {
        int node = nb + w * 4 + n;
        int j    = lane & 15;
        int e    = node * DEG + j;
        int src  = use64 ? (int)((const long long*)col)[e] : col[e];
        float sc = el1[node] + er1[src];
        sc = sc >= 0.f ? sc : SLOPE * sc;
        float mx = sc;
        #pragma unroll
        for (int m = 1; m < 16; m <<= 1) mx = fmaxf(mx, __shfl_xor(mx, m));
        float ex = __expf(sc - mx);
        float sm = ex;
        #pragma unroll
        for (int m = 1; m < 16; m <<= 1) sm += __shfl_xor(sm, m);
        float alpha = ex / sm;

        float a0 = 0.f, a1 = 0.f;
        #pragma unroll
        for (int jj = 0; jj < DEG; ++jj) {
            int   sj = __shfl(src, jj, 16);
            float aj = __shfl(alpha, jj, 16);
            unsigned int hv = *(const unsigned int*)&Hb[(size_t)sj * HID + lane * 2];
            a0 += aj * bf2f((unsigned short)(hv & 0xffffu));
            a1 += aj * bf2f((unsigned short)(hv >> 16));
        }
        a0 += b1[lane * 2];
        a1 += b1[lane * 2 + 1];
        unsigned int pk = (unsigned int)f2bf(a0) | ((unsigned int)f2bf(a1) << 16);
        *(unsigned int*)&at[(w * 4 + n) * STR + lane * 2] = pk;
    }
    __syncthreads();

    // ---- phase B: 16x64 GEMM, wave w owns col tile [w*16, w*16+16) ----
    f32x4 acc = {};
    const unsigned short* bb = w2t + (size_t)(w * 16 + ln) * HID;
    #pragma unroll
    for (int ks = 0; ks < HID / 32; ++ks) {
        bf16x8 af  = *(const bf16x8*)&at[ln * STR + ks * 32 + q * 8];
        bf16x8 bfr = *(const bf16x8*)&bb[ks * 32 + q * 8];
        acc = __builtin_amdgcn_mfma_f32_16x16x32_bf16(af, bfr, acc, 0, 0, 0);
    }

    float av = al2[w * 16 + ln], bv = ar2[w * 16 + ln];
    #pragma unroll
    for (int r = 0; r < 4; ++r) {
        float v  = acc[r];
        float sl = v * av, sr = v * bv;
        #pragma unroll
        for (int m = 1; m < 16; m <<= 1) {
            sl += __shfl_xor(sl, m);
            sr += __shfl_xor(sr, m);
        }
        int rowl = q * 4 + r;
        H2[(size_t)(nb + rowl) * OUT_F + w * 16 + ln] = f2bf(v);
        if (ln == 0) { redl[rowl][w] = sl; redr[rowl][w] = sr; }
    }
    __syncthreads();
    if (tid < 16) {
        el2[nb + tid] = redl[tid][0] + redl[tid][1] + redl[tid][2] + redl[tid][3];
        er2[nb + tid] = redr[tid][0] + redr[tid][1] + redr[tid][2] + redr[tid][3];
    }
}

// ---------- agg layer2: bf16 h gather (128B rows), fp32 out (+bias) ----------
__global__ void __launch_bounds__(256) agg2_k(
        const int* __restrict__ col, const int* __restrict__ flag64,
        const float* __restrict__ el, const float* __restrict__ er,
        const unsigned short* __restrict__ Hb, const float* __restrict__ bias,
        float* __restrict__ out) {
    int lane = threadIdx.x & 63;
    int node = blockIdx.x * 4 + (threadIdx.x >> 6);
    int j    = lane & 15;
    int e    = node * DEG + j;
    int src  = (*flag64) ? (int)((const long long*)col)[e] : col[e];
    float sc = el[node] + er[src];
    sc = sc >= 0.f ? sc : SLOPE * sc;
    float mx = sc;
    #pragma unroll
    for (int m = 1; m < 16; m <<= 1) mx = fmaxf(mx, __shfl_xor(mx, m));
    float ex = __expf(sc - mx);
    float sm = ex;
    #pragma unroll
    for (int m = 1; m < 16; m <<= 1) sm += __shfl_xor(sm, m);
    float alpha = ex / sm;

    float a0 = 0.f;
    #pragma unroll
    for (int jj = 0; jj < DEG; ++jj) {
        int   sj = __shfl(src, jj, 16);
        float aj = __shfl(alpha, jj, 16);
        a0 += aj * bf2f(Hb[(size_t)sj * OUT_F + lane]);
    }
    out[(size_t)node * OUT_F + lane] = a0 + bias[lane];
}

extern "C" void kernel_launch(void* const* d_in, const int* in_sizes, int n_in,
                              void* d_out, int out_size, void* d_ws, size_t ws_size,
                              hipStream_t stream) {
    const int*   row_ptr = (const int*)d_in[0];
    const int*   col_idx = (const int*)d_in[1];
    const float* x   = (const float*)d_in[2];
    const float* W1  = (const float*)d_in[3];
    const float* al1 = (const float*)d_in[4];
    const float* ar1 = (const float*)d_in[5];
    const float* b1  = (const float*)d_in[6];
    const float* W2  = (const float*)d_in[7];
    const float* al2 = (const float*)d_in[8];
    const float* ar2 = (const float*)d_in[9];
    const float* b2  = (const float*)d_in[10];
    float* out = (float*)d_out;

    float* ws = (float*)d_ws;
    unsigned short* h1b = (unsigned short*)ws;                 // 6.4M bf16
    unsigned short* h2b = (unsigned short*)(ws + 3200000);     // 3.2M bf16
    float* el1 = ws + 5000000;
    float* er1 = ws + 5050000;
    float* el2 = ws + 5100000;
    float* er2 = ws + 5150000;
    unsigned short* w1t = (unsigned short*)(ws + 5200000);     // 128*512 bf16
    unsigned short* w2t = (unsigned short*)(ws + 5232768);     // 64*128 bf16
    int* flag64 = (int*)(ws + 5236864);

    prep_kernel<<<(IN_F * HID + HID * OUT_F + 255) / 256, 256, 0, stream>>>(
        W1, W2, row_ptr, w1t, w2t, flag64);

    gemm1_reg<512, 128><<<(Nn + 63) / 64, 256, 0, stream>>>(
        x, w1t, al1, ar1, h1b, el1, er1, Nn);

    fused_agg_gemm2<<<Nn / 16, 256, 0, stream>>>(
        col_idx, flag64, el1, er1, h1b, b1, w2t, al2, ar2, h2b, el2, er2);

    agg2_k<<<Nn / 4, 256, 0, stream>>>(col_idx, flag64, el2, er2, h2b, b2, out);
}

// Round 5
// 265.712 us; speedup vs baseline: 1.0487x; 1.0487x over previous
//
#include <hip/hip_runtime.h>
#include <hip/hip_bf16.h>

#define Nn 50000
#define DEG 16
#define IN_F 512
#define HID 128
#define OUT_F 64
#define SLOPE 0.2f

typedef __attribute__((ext_vector_type(8))) short bf16x8;
typedef __attribute__((ext_vector_type(4))) float f32x4;
typedef __attribute__((ext_vector_type(2))) float f32x2;
typedef __attribute__((ext_vector_type(4))) unsigned int u32x4;

__device__ __forceinline__ unsigned short f2bf(float f) {
    return __builtin_bit_cast(unsigned short, __float2bfloat16(f));
}
__device__ __forceinline__ float bf2f(unsigned short u) {
    return __bfloat162float(__builtin_bit_cast(__hip_bfloat16, u));
}

// ---------- prep: W1/W2 -> [F][K] bf16. Coalesced READS, scattered writes ----------
__global__ void __launch_bounds__(256) prep_kernel(
        const float* __restrict__ W1, const float* __restrict__ W2,
        const int* __restrict__ row_ptr,
        unsigned short* __restrict__ w1t, unsigned short* __restrict__ w2t,
        int* __restrict__ flag64) {
    int g = blockIdx.x * 256 + threadIdx.x;
    if (g == 0) {
        // int32 layout: row_ptr words = [0,16,32,...]; int64: [0,0,16,0,...]
        *flag64 = (row_ptr[1] == DEG) ? 0 : 1;
    }
    if (g < IN_F * HID) {                     // read W1 linearly: k = g>>7, c = g&127
        int k = g >> 7, c = g & 127;
        w1t[c * IN_F + k] = f2bf(W1[g]);      // scattered 2B write (fire-and-forget)
    } else {
        int g2 = g - IN_F * HID;
        if (g2 < HID * OUT_F) {               // k = g2>>6, c = g2&63
            int k = g2 >> 6, c = g2 & 63;
            w2t[c * HID + k] = f2bf(W2[g2]);
        }
    }
}

// ---------- layer-1 GEMM: barrier-free, software-pipelined ----------
// 16 rows x 128 cols per wave, grid 782. Explicit double-buffered frags:
// at iter ks, issue ALL loads for ks+1 (2 A + 8 B) BEFORE the cvt+MFMA of
// ks — keeps ~10 KB/wave of VMEM in flight (no distance-1 vmcnt stalls).
template<int K, int F>
__global__ void __launch_bounds__(256, 3) gemm1_reg(
        const float* __restrict__ Af, const unsigned short* __restrict__ WT,
        const float* __restrict__ alv, const float* __restrict__ arv,
        unsigned short* __restrict__ Hb, float* __restrict__ el,
        float* __restrict__ er, int M) {
    constexpr int NT  = F / 16;
    constexpr int NKS = K / 32;
    const int tid  = threadIdx.x;
    const int lane = tid & 63;
    const int w    = tid >> 6;
    const int ln   = lane & 15, q = lane >> 4;
    const int mb   = blockIdx.x * 64 + w * 16;

    int m0 = mb + ln; if (m0 > M - 1) m0 = M - 1;
    const float* a0p = Af + (size_t)m0 * K;
    const unsigned short* bp = WT + (size_t)ln * K + q * 8;

    f32x4 acc[NT] = {};

    // prefetch ks = 0
    f32x4  va0 = *(const f32x4*)(a0p + q * 8);
    f32x4  va1 = *(const f32x4*)(a0p + q * 8 + 4);
    bf16x8 bn[NT];
    #pragma unroll
    for (int nt = 0; nt < NT; ++nt)
        bn[nt] = *(const bf16x8*)(bp + (size_t)nt * 16 * K);

    #pragma unroll
    for (int ks = 0; ks < NKS; ++ks) {
        f32x4  ca0 = va0, ca1 = va1;
        bf16x8 bc[NT];
        #pragma unroll
        for (int nt = 0; nt < NT; ++nt) bc[nt] = bn[nt];
        // issue next-iteration loads (clamped reload on the last iter)
        const int kn  = (ks + 1 < NKS) ? ks + 1 : ks;
        const int kkn = kn * 32;
        va0 = *(const f32x4*)(a0p + kkn + q * 8);
        va1 = *(const f32x4*)(a0p + kkn + q * 8 + 4);
        #pragma unroll
        for (int nt = 0; nt < NT; ++nt)
            bn[nt] = *(const bf16x8*)(bp + (size_t)nt * 16 * K + kkn);
        // compute current iteration
        bf16x8 af;
        #pragma unroll
        for (int jj = 0; jj < 4; ++jj) {
            af[jj]     = (short)f2bf(ca0[jj]);
            af[jj + 4] = (short)f2bf(ca1[jj]);
        }
        #pragma unroll
        for (int nt = 0; nt < NT; ++nt)
            acc[nt] = __builtin_amdgcn_mfma_f32_16x16x32_bf16(af, bc[nt], acc[nt], 0, 0, 0);
    }

    // ---- fused epilogue: bf16 H store + el/er row dots (pure in-wave) ----
    // D layout: col = ln, row = q*4 + reg  [measured m89/m91]
    float av[NT], bv[NT];
    #pragma unroll
    for (int nt = 0; nt < NT; ++nt) {
        av[nt] = alv[nt * 16 + ln];
        bv[nt] = arv[nt * 16 + ln];
    }
    #pragma unroll
    for (int r = 0; r < 4; ++r) {
        float sl = 0.f, sr = 0.f;
        #pragma unroll
        for (int nt = 0; nt < NT; ++nt) {
            float v = acc[nt][r];
            sl += v * av[nt];
            sr += v * bv[nt];
        }
        #pragma unroll
        for (int m = 1; m < 16; m <<= 1) {
            sl += __shfl_xor(sl, m);
            sr += __shfl_xor(sr, m);
        }
        int grow = mb + q * 4 + r;
        if (grow < M) {
            #pragma unroll
            for (int nt = 0; nt < NT; ++nt)
                Hb[(size_t)grow * F + nt * 16 + ln] = f2bf(acc[nt][r]);
            if (ln == 0) { el[grow] = sl; er[grow] = sr; }
        }
    }
}

// ---------- fused layer-1 aggregation + layer-2 GEMM + el2/er2 ----------
// Block = 16 nodes. Phase A: each 16-lane group owns one node (4 nodes/wave
// in parallel): softmax over its 16 edges, then per edge-broadcast each lane
// gathers 16B of the source row (one wave = 4 full 256B rows per iteration,
// 16 VMEM total). out1 tile -> LDS bf16 (never touches HBM).
// Phase B: 16x64 MFMA, K=128 from LDS (stride 136), W2T from L2; fused el2/er2.
__global__ void __launch_bounds__(256) fused_agg_gemm2(
        const int* __restrict__ col, const int* __restrict__ flag64,
        const float* __restrict__ el1, const float* __restrict__ er1,
        const unsigned short* __restrict__ Hb, const float* __restrict__ b1,
        const unsigned short* __restrict__ w2t,
        const float* __restrict__ al2, const float* __restrict__ ar2,
        unsigned short* __restrict__ H2, float* __restrict__ el2,
        float* __restrict__ er2) {
    constexpr int STR = 136;                  // 128 + 8 bf16 pad
    __shared__ unsigned short at[16 * STR];
    __shared__ float redl[16][4];
    __shared__ float redr[16][4];

    const int tid  = threadIdx.x;
    const int lane = tid & 63;
    const int w    = tid >> 6;
    const int ln   = lane & 15, q = lane >> 4;  // q doubles as node sub-index
    const int nb   = blockIdx.x * 16;
    const int use64 = *flag64;

    // ---- phase A: group q owns node nb + w*4 + q; lane ln = edge ----
    {
        int node = nb + w * 4 + q;
        int e    = node * DEG + ln;
        int src  = use64 ? (int)((const long long*)col)[e] : col[e];
        float sc = el1[node] + er1[src];
        sc = sc >= 0.f ? sc : SLOPE * sc;
        float mx = sc;
        #pragma unroll
        for (int m = 1; m < 16; m <<= 1) mx = fmaxf(mx, __shfl_xor(mx, m, 16));
        float ex = __expf(sc - mx);
        float sm = ex;
        #pragma unroll
        for (int m = 1; m < 16; m <<= 1) sm += __shfl_xor(sm, m, 16);
        float alpha = ex / sm;

        float a[8] = {};
        #pragma unroll
        for (int jj = 0; jj < DEG; ++jj) {
            int   sl_ = q * 16 + jj;          // own group's edge jj
            int   sj = __shfl(src, sl_);
            float aj = __shfl(alpha, sl_);
            bf16x8 hv = *(const bf16x8*)&Hb[(size_t)sj * HID + ln * 8];
            #pragma unroll
            for (int c = 0; c < 8; ++c)
                a[c] += aj * bf2f((unsigned short)hv[c]);
        }
        unsigned int pk[4];
        #pragma unroll
        for (int c = 0; c < 4; ++c) {
            float lo = a[2 * c]     + b1[ln * 8 + 2 * c];
            float hi = a[2 * c + 1] + b1[ln * 8 + 2 * c + 1];
            pk[c] = (unsigned int)f2bf(lo) | ((unsigned int)f2bf(hi) << 16);
        }
        *(u32x4*)&at[(w * 4 + q) * STR + ln * 8] = *(u32x4*)pk;
    }
    __syncthreads();

    // ---- phase B: 16x64 GEMM, wave w owns col tile [w*16, w*16+16) ----
    f32x4 acc = {};
    const unsigned short* bb = w2t + (size_t)(w * 16 + ln) * HID;
    #pragma unroll
    for (int ks = 0; ks < HID / 32; ++ks) {
        bf16x8 af  = *(const bf16x8*)&at[ln * STR + ks * 32 + q * 8];
        bf16x8 bfr = *(const bf16x8*)&bb[ks * 32 + q * 8];
        acc = __builtin_amdgcn_mfma_f32_16x16x32_bf16(af, bfr, acc, 0, 0, 0);
    }

    float av = al2[w * 16 + ln], bv = ar2[w * 16 + ln];
    #pragma unroll
    for (int r = 0; r < 4; ++r) {
        float v  = acc[r];
        float sl = v * av, sr = v * bv;
        #pragma unroll
        for (int m = 1; m < 16; m <<= 1) {
            sl += __shfl_xor(sl, m, 16);
            sr += __shfl_xor(sr, m, 16);
        }
        int rowl = q * 4 + r;
        H2[(size_t)(nb + rowl) * OUT_F + w * 16 + ln] = f2bf(v);
        if (ln == 0) { redl[rowl][w] = sl; redr[rowl][w] = sr; }
    }
    __syncthreads();
    if (tid < 16) {
        el2[nb + tid] = redl[tid][0] + redl[tid][1] + redl[tid][2] + redl[tid][3];
        er2[nb + tid] = redr[tid][0] + redr[tid][1] + redr[tid][2] + redr[tid][3];
    }
}

// ---------- agg layer2: one node/wave; paired-edge gather (full 128B rows) ----------
__global__ void __launch_bounds__(256) agg2_k(
        const int* __restrict__ col, const int* __restrict__ flag64,
        const float* __restrict__ el, const float* __restrict__ er,
        const unsigned short* __restrict__ Hb, const float* __restrict__ bias,
        float* __restrict__ out) {
    int lane = threadIdx.x & 63;
    int node = blockIdx.x * 4 + (threadIdx.x >> 6);
    int j    = lane & 15;
    int e    = node * DEG + j;
    int src  = (*flag64) ? (int)((const long long*)col)[e] : col[e];
    float sc = el[node] + er[src];
    sc = sc >= 0.f ? sc : SLOPE * sc;
    float mx = sc;
    #pragma unroll
    for (int m = 1; m < 16; m <<= 1) mx = fmaxf(mx, __shfl_xor(mx, m, 16));
    float ex = __expf(sc - mx);
    float sm = ex;
    #pragma unroll
    for (int m = 1; m < 16; m <<= 1) sm += __shfl_xor(sm, m, 16);
    float alpha = ex / sm;

    // half-wave h handles edge jj+h; 32 lanes x 4B cover the 128B row
    int h = lane >> 5;
    int c = lane & 31;
    float a0 = 0.f, a1 = 0.f;
    #pragma unroll
    for (int jj = 0; jj < DEG; jj += 2) {
        int   sj = __shfl(src, jj + h, 16);
        float aj = __shfl(alpha, jj + h, 16);
        unsigned int hv = *(const unsigned int*)&Hb[(size_t)sj * OUT_F + c * 2];
        a0 += aj * bf2f((unsigned short)(hv & 0xffffu));
        a1 += aj * bf2f((unsigned short)(hv >> 16));
    }
    a0 += __shfl_xor(a0, 32);
    a1 += __shfl_xor(a1, 32);
    if (h == 0) {
        f32x2 o;
        o[0] = a0 + bias[c * 2];
        o[1] = a1 + bias[c * 2 + 1];
        *(f32x2*)&out[(size_t)node * OUT_F + c * 2] = o;
    }
}

extern "C" void kernel_launch(void* const* d_in, const int* in_sizes, int n_in,
                              void* d_out, int out_size, void* d_ws, size_t ws_size,
                              hipStream_t stream) {
    const int*   row_ptr = (const int*)d_in[0];
    const int*   col_idx = (const int*)d_in[1];
    const float* x   = (const float*)d_in[2];
    const float* W1  = (const float*)d_in[3];
    const float* al1 = (const float*)d_in[4];
    const float* ar1 = (const float*)d_in[5];
    const float* b1  = (const float*)d_in[6];
    const float* W2  = (const float*)d_in[7];
    const float* al2 = (const float*)d_in[8];
    const float* ar2 = (const float*)d_in[9];
    const float* b2  = (const float*)d_in[10];
    float* out = (float*)d_out;

    float* ws = (float*)d_ws;
    unsigned short* h1b = (unsigned short*)ws;                 // 6.4M bf16
    unsigned short* h2b = (unsigned short*)(ws + 3200000);     // 3.2M bf16
    float* el1 = ws + 5000000;
    float* er1 = ws + 5050000;
    float* el2 = ws + 5100000;
    float* er2 = ws + 5150000;
    unsigned short* w1t = (unsigned short*)(ws + 5200000);     // 128*512 bf16
    unsigned short* w2t = (unsigned short*)(ws + 5232768);     // 64*128 bf16
    int* flag64 = (int*)(ws + 5236864);

    prep_kernel<<<(IN_F * HID + HID * OUT_F + 255) / 256, 256, 0, stream>>>(
        W1, W2, row_ptr, w1t, w2t, flag64);

    gemm1_reg<512, 128><<<(Nn + 63) / 64, 256, 0, stream>>>(
        x, w1t, al1, ar1, h1b, el1, er1, Nn);

    fused_agg_gemm2<<<Nn / 16, 256, 0, stream>>>(
        col_idx, flag64, el1, er1, h1b, b1, w2t, al2, ar2, h2b, el2, er2);

    agg2_k<<<Nn / 4, 256, 0, stream>>>(col_idx, flag64, el2, er2, h2b, b2, out);
}

// Round 6
// 235.243 us; speedup vs baseline: 1.1846x; 1.1295x over previous
//
#include <hip/hip_runtime.h>
#include <hip/hip_bf16.h>

#define Nn 50000
#define DEG 16
#define IN_F 512
#define HID 128
#define OUT_F 64
#define SLOPE 0.2f

typedef __attribute__((ext_vector_type(8))) short bf16x8;
typedef __attribute__((ext_vector_type(4))) float f32x4;
typedef __attribute__((ext_vector_type(2))) float f32x2;
typedef __attribute__((ext_vector_type(4))) unsigned int u32x4;

__device__ __forceinline__ unsigned short f2bf(float f) {
    return __builtin_bit_cast(unsigned short, __float2bfloat16(f));
}
__device__ __forceinline__ float bf2f(unsigned short u) {
    return __bfloat162float(__builtin_bit_cast(__hip_bfloat16, u));
}
__device__ __forceinline__ void async_copy16(const void* g, void* l) {
    __builtin_amdgcn_global_load_lds(
        (const __attribute__((address_space(1))) unsigned int*)g,
        (__attribute__((address_space(3))) unsigned int*)l, 16, 0, 0);
}

// ---------- prep ----------
// w1c: chunked+swizzled W1^T for async-LDS staging: [ch][c][s'] with
// ch = k>>7, s = (k&127)>>3 (16B sub-block), s' = s ^ (c&7), j = k&7.
// Each 32KB chunk is contiguous (global_load_lds needs lane-contiguity);
// the XOR swizzle makes gemm1's ds_read_b128 frag reads <=2-way conflicted.
// w2t stays [F][K] for the fused kernel.
__global__ void __launch_bounds__(256) prep_kernel(
        const float* __restrict__ W1, const float* __restrict__ W2,
        const int* __restrict__ row_ptr,
        unsigned short* __restrict__ w1c, unsigned short* __restrict__ w2t,
        int* __restrict__ flag64) {
    int g = blockIdx.x * 256 + threadIdx.x;
    if (g == 0) {
        // int32 layout: row_ptr words = [0,16,32,...]; int64: [0,0,16,0,...]
        *flag64 = (row_ptr[1] == DEG) ? 0 : 1;
    }
    if (g < IN_F * HID) {                     // read W1 linearly: k = g>>7, c = g&127
        int k = g >> 7, c = g & 127;
        int ch = k >> 7, kl = k & 127;
        int s  = kl >> 3, j = kl & 7;
        int sp = s ^ (c & 7);
        w1c[ch * 16384 + c * 128 + sp * 8 + j] = f2bf(W1[g]);
    } else {
        int g2 = g - IN_F * HID;
        if (g2 < HID * OUT_F) {               // k = g2>>6, c = g2&63
            int k = g2 >> 6, c = g2 & 63;
            w2t[c * HID + k] = f2bf(W2[g2]);
        }
    }
}

// ---------- layer-1 GEMM: async-LDS B staging + direct-A + fused el/er ----------
// Block 256 = 4 waves; wave tile 16 rows x 128 cols (A rows private ->
// direct global f32x4 loads, hoisted per chunk). B chunk (128x128 bf16,
// 32 KB) staged via global_load_lds width=16 (no VGPR round-trip; the
// __syncthreads drains vmcnt). Frag reads use the prep-time XOR swizzle.
template<int K>
__global__ void __launch_bounds__(256) gemm1_lds(
        const float* __restrict__ Af, const unsigned short* __restrict__ w1c,
        const float* __restrict__ alv, const float* __restrict__ arv,
        unsigned short* __restrict__ Hb, float* __restrict__ el,
        float* __restrict__ er, int M) {
    constexpr int F   = 128;
    constexpr int NT  = 8;
    constexpr int NCH = K / 128;
    __shared__ unsigned short bt[128 * 128];   // 32 KB chunk of W1^T

    const int tid  = threadIdx.x;
    const int lane = tid & 63;
    const int w    = tid >> 6;
    const int ln   = lane & 15, q = lane >> 4;
    const int mb   = blockIdx.x * 64 + w * 16;

    int m0 = mb + ln; if (m0 > M - 1) m0 = M - 1;
    const float* a0p = Af + (size_t)m0 * K;

    f32x4 acc[NT] = {};

    for (int ch = 0; ch < NCH; ++ch) {
        // ---- async-stage B chunk: 32 instrs x 1KB, wave w does slots [w*8, w*8+8) ----
        const char* gch = (const char*)w1c + ch * 32768;
        #pragma unroll
        for (int i = 0; i < 8; ++i) {
            int slot = w * 8 + i;
            async_copy16(gch + slot * 1024 + lane * 16, (char*)bt + slot * 1024);
        }
        __syncthreads();                       // drains vmcnt(0) incl. the DMA

        // ---- hoist this chunk's 8 A-loads (all independent, stay in flight) ----
        f32x4 ap[4][2];
        #pragma unroll
        for (int ks = 0; ks < 4; ++ks) {
            const int kk = ch * 128 + ks * 32 + q * 8;
            ap[ks][0] = *(const f32x4*)(a0p + kk);
            ap[ks][1] = *(const f32x4*)(a0p + kk + 4);
        }
        #pragma unroll
        for (int ks = 0; ks < 4; ++ks) {
            bf16x8 af;
            #pragma unroll
            for (int jj = 0; jj < 4; ++jj) {
                af[jj]     = (short)f2bf(ap[ks][0][jj]);
                af[jj + 4] = (short)f2bf(ap[ks][1][jj]);
            }
            #pragma unroll
            for (int nt = 0; nt < NT; ++nt) {
                const int c  = nt * 16 + ln;
                const int sp = (ks * 4 + q) ^ (ln & 7);   // undo prep swizzle
                bf16x8 bfr = *(const bf16x8*)&bt[c * 128 + sp * 8];
                acc[nt] = __builtin_amdgcn_mfma_f32_16x16x32_bf16(af, bfr, acc[nt], 0, 0, 0);
            }
        }
        __syncthreads();                       // before next chunk overwrites bt
    }

    // ---- fused epilogue: bf16 H store + el/er row dots (pure in-wave) ----
    // D layout: col = ln, row = q*4 + reg  [measured m89/m91]
    float av[NT], bv[NT];
    #pragma unroll
    for (int nt = 0; nt < NT; ++nt) {
        av[nt] = alv[nt * 16 + ln];
        bv[nt] = arv[nt * 16 + ln];
    }
    #pragma unroll
    for (int r = 0; r < 4; ++r) {
        float sl = 0.f, sr = 0.f;
        #pragma unroll
        for (int nt = 0; nt < NT; ++nt) {
            float v = acc[nt][r];
            sl += v * av[nt];
            sr += v * bv[nt];
        }
        #pragma unroll
        for (int m = 1; m < 16; m <<= 1) {
            sl += __shfl_xor(sl, m);
            sr += __shfl_xor(sr, m);
        }
        int grow = mb + q * 4 + r;
        if (grow < M) {
            #pragma unroll
            for (int nt = 0; nt < NT; ++nt)
                Hb[(size_t)grow * F + nt * 16 + ln] = f2bf(acc[nt][r]);
            if (ln == 0) { el[grow] = sl; er[grow] = sr; }
        }
    }
}

// ---------- fused layer-1 aggregation + layer-2 GEMM + el2/er2 ----------
// Block = 16 nodes. Phase A: each 16-lane group owns one node (4 nodes/wave
// in parallel): softmax over its 16 edges, then per edge-broadcast each lane
// gathers 16B of the source row (one wave = 4 full 256B rows per iteration,
// 16 VMEM total). out1 tile -> LDS bf16 (never touches HBM).
// Phase B: 16x64 MFMA, K=128 from LDS (stride 136), W2T from L2; fused el2/er2.
__global__ void __launch_bounds__(256) fused_agg_gemm2(
        const int* __restrict__ col, const int* __restrict__ flag64,
        const float* __restrict__ el1, const float* __restrict__ er1,
        const unsigned short* __restrict__ Hb, const float* __restrict__ b1,
        const unsigned short* __restrict__ w2t,
        const float* __restrict__ al2, const float* __restrict__ ar2,
        unsigned short* __restrict__ H2, float* __restrict__ el2,
        float* __restrict__ er2) {
    constexpr int STR = 136;                  // 128 + 8 bf16 pad
    __shared__ unsigned short at[16 * STR];
    __shared__ float redl[16][4];
    __shared__ float redr[16][4];

    const int tid  = threadIdx.x;
    const int lane = tid & 63;
    const int w    = tid >> 6;
    const int ln   = lane & 15, q = lane >> 4;  // q doubles as node sub-index
    const int nb   = blockIdx.x * 16;
    const int use64 = *flag64;

    // ---- phase A: group q owns node nb + w*4 + q; lane ln = edge ----
    {
        int node = nb + w * 4 + q;
        int e    = node * DEG + ln;
        int src  = use64 ? (int)((const long long*)col)[e] : col[e];
        float sc = el1[node] + er1[src];
        sc = sc >= 0.f ? sc : SLOPE * sc;
        float mx = sc;
        #pragma unroll
        for (int m = 1; m < 16; m <<= 1) mx = fmaxf(mx, __shfl_xor(mx, m, 16));
        float ex = __expf(sc - mx);
        float sm = ex;
        #pragma unroll
        for (int m = 1; m < 16; m <<= 1) sm += __shfl_xor(sm, m, 16);
        float alpha = ex / sm;

        float a[8] = {};
        #pragma unroll
        for (int jj = 0; jj < DEG; ++jj) {
            int   sl_ = q * 16 + jj;          // own group's edge jj
            int   sj = __shfl(src, sl_);
            float aj = __shfl(alpha, sl_);
            bf16x8 hv = *(const bf16x8*)&Hb[(size_t)sj * HID + ln * 8];
            #pragma unroll
            for (int c = 0; c < 8; ++c)
                a[c] += aj * bf2f((unsigned short)hv[c]);
        }
        unsigned int pk[4];
        #pragma unroll
        for (int c = 0; c < 4; ++c) {
            float lo = a[2 * c]     + b1[ln * 8 + 2 * c];
            float hi = a[2 * c + 1] + b1[ln * 8 + 2 * c + 1];
            pk[c] = (unsigned int)f2bf(lo) | ((unsigned int)f2bf(hi) << 16);
        }
        *(u32x4*)&at[(w * 4 + q) * STR + ln * 8] = *(u32x4*)pk;
    }
    __syncthreads();

    // ---- phase B: 16x64 GEMM, wave w owns col tile [w*16, w*16+16) ----
    f32x4 acc = {};
    const unsigned short* bb = w2t + (size_t)(w * 16 + ln) * HID;
    #pragma unroll
    for (int ks = 0; ks < HID / 32; ++ks) {
        bf16x8 af  = *(const bf16x8*)&at[ln * STR + ks * 32 + q * 8];
        bf16x8 bfr = *(const bf16x8*)&bb[ks * 32 + q * 8];
        acc = __builtin_amdgcn_mfma_f32_16x16x32_bf16(af, bfr, acc, 0, 0, 0);
    }

    float av = al2[w * 16 + ln], bv = ar2[w * 16 + ln];
    #pragma unroll
    for (int r = 0; r < 4; ++r) {
        float v  = acc[r];
        float sl = v * av, sr = v * bv;
        #pragma unroll
        for (int m = 1; m < 16; m <<= 1) {
            sl += __shfl_xor(sl, m, 16);
            sr += __shfl_xor(sr, m, 16);
        }
        int rowl = q * 4 + r;
        H2[(size_t)(nb + rowl) * OUT_F + w * 16 + ln] = f2bf(v);
        if (ln == 0) { redl[rowl][w] = sl; redr[rowl][w] = sr; }
    }
    __syncthreads();
    if (tid < 16) {
        el2[nb + tid] = redl[tid][0] + redl[tid][1] + redl[tid][2] + redl[tid][3];
        er2[nb + tid] = redr[tid][0] + redr[tid][1] + redr[tid][2] + redr[tid][3];
    }
}

// ---------- agg layer2: one node/16-lane-group; paired-edge gather ----------
__global__ void __launch_bounds__(256) agg2_k(
        const int* __restrict__ col, const int* __restrict__ flag64,
        const float* __restrict__ el, const float* __restrict__ er,
        const unsigned short* __restrict__ Hb, const float* __restrict__ bias,
        float* __restrict__ out) {
    int lane = threadIdx.x & 63;
    int node = blockIdx.x * 4 + (threadIdx.x >> 6);
    int j    = lane & 15;
    int e    = node * DEG + j;
    int src  = (*flag64) ? (int)((const long long*)col)[e] : col[e];
    float sc = el[node] + er[src];
    sc = sc >= 0.f ? sc : SLOPE * sc;
    float mx = sc;
    #pragma unroll
    for (int m = 1; m < 16; m <<= 1) mx = fmaxf(mx, __shfl_xor(mx, m, 16));
    float ex = __expf(sc - mx);
    float sm = ex;
    #pragma unroll
    for (int m = 1; m < 16; m <<= 1) sm += __shfl_xor(sm, m, 16);
    float alpha = ex / sm;

    // half-wave h handles edge jj+h; 32 lanes x 4B cover the 128B row
    int h = lane >> 5;
    int c = lane & 31;
    float a0 = 0.f, a1 = 0.f;
    #pragma unroll
    for (int jj = 0; jj < DEG; jj += 2) {
        int   sj = __shfl(src, jj + h, 16);
        float aj = __shfl(alpha, jj + h, 16);
        unsigned int hv = *(const unsigned int*)&Hb[(size_t)sj * OUT_F + c * 2];
        a0 += aj * bf2f((unsigned short)(hv & 0xffffu));
        a1 += aj * bf2f((unsigned short)(hv >> 16));
    }
    a0 += __shfl_xor(a0, 32);
    a1 += __shfl_xor(a1, 32);
    if (h == 0) {
        f32x2 o;
        o[0] = a0 + bias[c * 2];
        o[1] = a1 + bias[c * 2 + 1];
        *(f32x2*)&out[(size_t)node * OUT_F + c * 2] = o;
    }
}

extern "C" void kernel_launch(void* const* d_in, const int* in_sizes, int n_in,
                              void* d_out, int out_size, void* d_ws, size_t ws_size,
                              hipStream_t stream) {
    const int*   row_ptr = (const int*)d_in[0];
    const int*   col_idx = (const int*)d_in[1];
    const float* x   = (const float*)d_in[2];
    const float* W1  = (const float*)d_in[3];
    const float* al1 = (const float*)d_in[4];
    const float* ar1 = (const float*)d_in[5];
    const float* b1  = (const float*)d_in[6];
    const float* W2  = (const float*)d_in[7];
    const float* al2 = (const float*)d_in[8];
    const float* ar2 = (const float*)d_in[9];
    const float* b2  = (const float*)d_in[10];
    float* out = (float*)d_out;

    float* ws = (float*)d_ws;
    unsigned short* h1b = (unsigned short*)ws;                 // 6.4M bf16
    unsigned short* h2b = (unsigned short*)(ws + 3200000);     // 3.2M bf16
    float* el1 = ws + 5000000;
    float* er1 = ws + 5050000;
    float* el2 = ws + 5100000;
    float* er2 = ws + 5150000;
    unsigned short* w1c = (unsigned short*)(ws + 5200000);     // 128*512 bf16 (chunked+swizzled)
    unsigned short* w2t = (unsigned short*)(ws + 5232768);     // 64*128 bf16
    int* flag64 = (int*)(ws + 5236864);

    prep_kernel<<<(IN_F * HID + HID * OUT_F + 255) / 256, 256, 0, stream>>>(
        W1, W2, row_ptr, w1c, w2t, flag64);

    gemm1_lds<512><<<(Nn + 63) / 64, 256, 0, stream>>>(
        x, w1c, al1, ar1, h1b, el1, er1, Nn);

    fused_agg_gemm2<<<Nn / 16, 256, 0, stream>>>(
        col_idx, flag64, el1, er1, h1b, b1, w2t, al2, ar2, h2b, el2, er2);

    agg2_k<<<Nn / 4, 256, 0, stream>>>(col_idx, flag64, el2, er2, h2b, b2, out);
}